// Round 3
// baseline (211.706 us; speedup 1.0000x reference)
//
#include <hip/hip_runtime.h>
#include <hip/hip_bf16.h>

typedef __attribute__((ext_vector_type(8))) short bf16x8;
typedef __attribute__((ext_vector_type(4))) float f32x4;
typedef unsigned short u16;

#define BATCH 12288

__device__ __forceinline__ u16 f2bf(float f){
  __hip_bfloat16 h = __float2bfloat16(f);
  return *reinterpret_cast<u16*>(&h);
}
__device__ __forceinline__ float bf2f(u16 u){
  __hip_bfloat16 h; *reinterpret_cast<u16*>(&h) = u;
  return __bfloat162float(h);
}
__device__ __forceinline__ f32x4 mfma16(bf16x8 a, bf16x8 b, f32x4 c){
  return __builtin_amdgcn_mfma_f32_16x16x32_bf16(a, b, c, 0, 0, 0);
}
__device__ __forceinline__ float softplusf(float v){ return log1pf(expf(v)); }

// ---------------- K0: all 8 weight matrices -> zero-padded [128][128] bf16 slabs
__global__ __launch_bounds__(256) void k_wconv8(
    const float* __restrict__ s0, const float* __restrict__ s1,
    const float* __restrict__ s2, const float* __restrict__ s3,
    const float* __restrict__ s4, const float* __restrict__ s5,
    const float* __restrict__ s6, const float* __restrict__ s7,
    u16* __restrict__ dst)
{
  int blk = blockIdx.x;            // 512 blocks: 8 slabs x 64
  int slab = blk >> 6;
  const float* src; int rows, cols;
  switch (slab){
    case 0: src = s0; rows = 118; cols = 128; break;
    case 1: src = s1; rows = 118; cols = 128; break;
    case 2: src = s2; rows = 109; cols = 118; break;
    case 3: src = s3; rows = 109; cols = 128; break;
    case 4: src = s4; rows = 100; cols = 109; break;
    case 5: src = s5; rows = 100; cols = 128; break;
    case 6: src = s6; rows =  92; cols = 100; break;
    default: src = s7; rows =  92; cols = 128; break;
  }
  int idx = (blk & 63) * 256 + threadIdx.x;       // 16384 per slab
  int r = idx >> 7, c = idx & 127;
  float v = (r < rows && c < cols) ? src[r * cols + c] : 0.f;
  dst[slab * 16384 + idx] = f2bf(v);
}

// ---------------- K1: 4-layer compression MLP via MFMA (32 rows / block)
__global__ __launch_bounds__(256) void k_mlp(const float* __restrict__ x,
    const u16* __restrict__ slabs,
    const float* __restrict__ cb0, const float* __restrict__ cb1,
    const float* __restrict__ cb2, const float* __restrict__ cb3,
    const float* __restrict__ sb0, const float* __restrict__ sb1,
    const float* __restrict__ sb2, const float* __restrict__ sb3,
    float* __restrict__ comp)
{
  const int LSTR = 136;                       // LDS row stride (bf16 elems)
  __shared__ u16 xbf[32 * 136];
  __shared__ u16 act[2][32 * 136];
  int tid = threadIdx.x;
  int lane = tid & 63, w = tid >> 6;
  int fr = lane & 15, fg = lane >> 4;
  int r0 = blockIdx.x * 32;

  // stage x (f32 -> bf16) into LDS
  #pragma unroll
  for (int i = 0; i < 4; i++){
    int slot = tid + i * 256;                 // 1024 float4 slots = 32 rows * 32
    int row = slot >> 5, c4 = slot & 31;
    float4 v = *reinterpret_cast<const float4*>(&x[(r0 + row) * 128 + c4 * 4]);
    ushort4 pk;
    pk.x = f2bf(v.x); pk.y = f2bf(v.y); pk.z = f2bf(v.z); pk.w = f2bf(v.w);
    *reinterpret_cast<ushort4*>(&xbf[row * LSTR + c4 * 4]) = pk;
  }
  __syncthreads();

  // x A-fragments kept in registers for all skip GEMMs
  bf16x8 xa[2][4];
  #pragma unroll
  for (int mf = 0; mf < 2; mf++)
    #pragma unroll
    for (int kc = 0; kc < 4; kc++)
      xa[mf][kc] = *reinterpret_cast<const bf16x8*>(&xbf[(16*mf + fr) * LSTR + kc*32 + fg*8]);

  const float* cbs[4] = {cb0, cb1, cb2, cb3};
  const float* sbs[4] = {sb0, sb1, sb2, sb3};
  const int douts[4] = {118, 109, 100, 92};

  #pragma unroll
  for (int s = 0; s < 4; s++){
    const u16* aIn  = (s == 0) ? xbf : &act[(s + 1) & 1][0];
    u16*       aOut = &act[s & 1][0];
    const u16* cwS = slabs + (2*s)     * 16384;
    const u16* swS = slabs + (2*s + 1) * 16384;
    const float* cb = cbs[s];
    const float* sb = sbs[s];
    int dout = douts[s];

    bf16x8 af[2][4];
    #pragma unroll
    for (int mf = 0; mf < 2; mf++)
      #pragma unroll
      for (int kc = 0; kc < 4; kc++)
        af[mf][kc] = *reinterpret_cast<const bf16x8*>(&aIn[(16*mf + fr) * LSTR + kc*32 + fg*8]);

    f32x4 ac1[2][2], ac2[2][2];
    #pragma unroll
    for (int mf = 0; mf < 2; mf++)
      #pragma unroll
      for (int nf = 0; nf < 2; nf++){
        ac1[mf][nf] = (f32x4){0.f,0.f,0.f,0.f};
        ac2[mf][nf] = (f32x4){0.f,0.f,0.f,0.f};
      }

    #pragma unroll
    for (int nf = 0; nf < 2; nf++){
      int o = 32*w + 16*nf + fr;              // output col this lane supplies as B-row
      #pragma unroll
      for (int kc = 0; kc < 4; kc++){
        bf16x8 b1 = *reinterpret_cast<const bf16x8*>(&cwS[o * 128 + kc*32 + fg*8]);
        bf16x8 b2 = *reinterpret_cast<const bf16x8*>(&swS[o * 128 + kc*32 + fg*8]);
        ac1[0][nf] = mfma16(af[0][kc], b1, ac1[0][nf]);
        ac1[1][nf] = mfma16(af[1][kc], b1, ac1[1][nf]);
        ac2[0][nf] = mfma16(xa[0][kc], b2, ac2[0][nf]);
        ac2[1][nf] = mfma16(xa[1][kc], b2, ac2[1][nf]);
      }
    }

    #pragma unroll
    for (int nf = 0; nf < 2; nf++){
      int col = 32*w + 16*nf + fr;
      float cbv = (col < dout) ? cb[col] : 0.f;
      float sbv = (col < dout) ? sb[col] : 0.f;
      #pragma unroll
      for (int mf = 0; mf < 2; mf++){
        #pragma unroll
        for (int r = 0; r < 4; r++){
          float t1 = ac1[mf][nf][r] + cbv;
          float g = 0.5f * t1 * (1.f + erff(t1 * 0.70710678118654752f));
          float v = g + 0.1f * (ac2[mf][nf][r] + sbv);
          int row = 16*mf + fg*4 + r;
          if (s < 3){
            aOut[row * LSTR + col] = (col < dout) ? f2bf(v) : (u16)0;
          } else {
            if (col < 92) comp[(r0 + row) * 92 + col] = v;
          }
        }
      }
    }
    __syncthreads();
  }
}

// ---------------- K2a: per-row finalize: bf16 C (padded 96), -0.5*norms, energy, basin probs
__global__ __launch_bounds__(256) void k_rowfin(const float* __restrict__ comp,
    u16* __restrict__ Cbf, float* __restrict__ nrm2,
    const float* __restrict__ basin_c, const float* __restrict__ basin_d,
    const float* __restrict__ basin_w,
    float* __restrict__ energy_out, float* __restrict__ probs_out)
{
  int tid = threadIdx.x; int lane = tid & 63; int w = tid >> 6;
  int row = blockIdx.x * 4 + w;

  float c0 = comp[row * 92 + lane];
  int d2i = 64 + lane;
  float c1 = (d2i < 92) ? comp[row * 92 + d2i] : 0.f;

  u16 b0 = f2bf(c0);
  u16 b1 = (d2i < 92) ? f2bf(c1) : (u16)0;
  Cbf[row * 96 + lane] = b0;
  if (lane < 32) Cbf[row * 96 + 64 + lane] = b1;   // cols 64..95 (92..95 zero pad)

  // row norm from the *bf16* values (consistency with MFMA gram); store -0.5*|c|^2
  float f0 = bf2f(b0), f1 = bf2f(b1);
  float ns = f0*f0 + f1*f1;
  #pragma unroll
  for (int m = 1; m < 64; m <<= 1) ns += __shfl_xor(ns, m);
  if (lane == 0) nrm2[row] = -0.5f * ns;

  // basin distances (f32 compressed)
  float bd[8];
  #pragma unroll
  for (int b = 0; b < 8; b++){
    float e0 = c0 - basin_c[b * 92 + lane];
    float p = e0 * e0;
    if (d2i < 92){ float e1 = c1 - basin_c[b * 92 + d2i]; p += e1 * e1; }
    #pragma unroll
    for (int m = 1; m < 64; m <<= 1) p += __shfl_xor(p, m);
    bd[b] = sqrtf(p);
  }
  float z[8]; float mx = -1e30f;
  #pragma unroll
  for (int b = 0; b < 8; b++){
    float wd = softplusf(basin_w[b]);
    z[b] = -bd[b] / wd;
    mx = fmaxf(mx, z[b]);
  }
  float p8[8]; float ssum = 0.f;
  #pragma unroll
  for (int b = 0; b < 8; b++){ p8[b] = expf(z[b] - mx); ssum += p8[b]; }
  float inv = 1.f / ssum; float en = 0.f;
  #pragma unroll
  for (int b = 0; b < 8; b++){ p8[b] *= inv; en += p8[b] * basin_d[b]; }

  if (lane == 0) energy_out[row] = en;
  if (lane < 8){
    float v = (lane & 4) ? ((lane & 2) ? ((lane & 1) ? p8[7] : p8[6])
                                       : ((lane & 1) ? p8[5] : p8[4]))
                         : ((lane & 2) ? ((lane & 1) ? p8[3] : p8[2])
                                       : ((lane & 1) ? p8[1] : p8[0]));
    probs_out[row * 8 + lane] = v;
  }
}

// ---------------- K2b: pairwise-distance shell histogram via bf16 MFMA gram
// C-init trick: accum starts at -0.5(|a|^2+|b|^2); after gram MFMAs, D = -0.5*d^2.
// Shell test d^2 >= q  <=>  D <= -q/2 (precomputed). 27 KB LDS -> 4 blocks/CU.
__global__ __launch_bounds__(256, 4) void k_pdist(const u16* __restrict__ Cbf,
    const float* __restrict__ nrm2, const float* __restrict__ shell_bnd,
    unsigned* __restrict__ cnt)
{
  __shared__ u16 Bs[2][64 * 104];   // 104-elem stride: 13x16B granules, conflict-benign
  __shared__ float Ns[2][64];
  int tid = threadIdx.x; int lane = tid & 63; int w = tid >> 6;
  int fr = lane & 15, fg = lane >> 4;
  int blk = blockIdx.x;
  int ib = blk % 96, jc = blk / 96;         // 96 i-tiles x 32 j-chunks
  int i0 = ib * 128, j0 = jc * 384;

  float q0 = softplusf(shell_bnd[0]); float mq0 = -0.5f * q0 * q0;
  float q1 = softplusf(shell_bnd[1]); float mq1 = -0.5f * q1 * q1;
  float q2 = softplusf(shell_bnd[2]); float mq2 = -0.5f * q2 * q2;
  float q3 = softplusf(shell_bnd[3]); float mq3 = -0.5f * q3 * q3;

  int wrow0 = i0 + 32 * w;
  bf16x8 A[2][3];
  #pragma unroll
  for (int mf = 0; mf < 2; mf++)
    #pragma unroll
    for (int kc = 0; kc < 3; kc++)
      A[mf][kc] = *reinterpret_cast<const bf16x8*>(&Cbf[(wrow0 + 16*mf + fr) * 96 + kc*32 + fg*8]);

  float hr[2][4];                            // -0.5*|row|^2
  #pragma unroll
  for (int mf = 0; mf < 2; mf++)
    #pragma unroll
    for (int r = 0; r < 4; r++)
      hr[mf][r] = nrm2[wrow0 + 16*mf + fg*4 + r];

  unsigned c[2][4][4];
  #pragma unroll
  for (int mf = 0; mf < 2; mf++)
    #pragma unroll
    for (int r = 0; r < 4; r++)
      #pragma unroll
      for (int t = 0; t < 4; t++) c[mf][r][t] = 0u;

  // staging offsets (hoisted)
  int ofsL[3], ofsR[3], ofsS[3];
  #pragma unroll
  for (int t = 0; t < 3; t++){
    int ch = tid + t * 256;                  // 768 chunks of 16B = 64 rows x 12
    int rr = ch / 12, sl = ch - rr * 12;
    ofsR[t] = rr; ofsS[t] = sl * 8;
    ofsL[t] = rr * 104 + sl * 8;
  }

  bf16x8 rv[3]; float nsv = 0.f;
  auto stage_load = [&](int st){
    int jr0 = j0 + st * 64;
    #pragma unroll
    for (int t = 0; t < 3; t++)
      rv[t] = *reinterpret_cast<const bf16x8*>(&Cbf[(jr0 + ofsR[t]) * 96 + ofsS[t]]);
    if (tid < 64) nsv = nrm2[jr0 + tid];
  };
  auto stage_write = [&](int p){
    #pragma unroll
    for (int t = 0; t < 3; t++)
      *reinterpret_cast<bf16x8*>(&Bs[p][ofsL[t]]) = rv[t];
    if (tid < 64) Ns[p][tid] = nsv;
  };

  stage_load(0); stage_write(0);
  __syncthreads();

  for (int s = 0; s < 6; s++){
    int p = s & 1;
    if (s < 5) stage_load(s + 1);            // issue early: latency hides under compute

    #pragma unroll
    for (int nt = 0; nt < 4; nt++){
      bf16x8 B0 = *reinterpret_cast<const bf16x8*>(&Bs[p][(nt*16 + fr) * 104 + 0*32 + fg*8]);
      bf16x8 B1 = *reinterpret_cast<const bf16x8*>(&Bs[p][(nt*16 + fr) * 104 + 1*32 + fg*8]);
      bf16x8 B2 = *reinterpret_cast<const bf16x8*>(&Bs[p][(nt*16 + fr) * 104 + 2*32 + fg*8]);
      float hc = Ns[p][nt*16 + fr];

      f32x4 g0, g1;
      #pragma unroll
      for (int r = 0; r < 4; r++){ g0[r] = hr[0][r] + hc; g1[r] = hr[1][r] + hc; }
      g0 = mfma16(A[0][0], B0, g0); g0 = mfma16(A[0][1], B1, g0); g0 = mfma16(A[0][2], B2, g0);
      g1 = mfma16(A[1][0], B0, g1); g1 = mfma16(A[1][1], B1, g1); g1 = mfma16(A[1][2], B2, g1);

      #pragma unroll
      for (int r = 0; r < 4; r++){
        float v0 = g0[r], v1 = g1[r];
        c[0][r][0] += (v0 <= mq0);
        c[0][r][1] += (v0 <= mq1);
        c[0][r][2] += (v0 <= mq2);
        c[0][r][3] += (v0 <= mq3);
        c[1][r][0] += (v1 <= mq0);
        c[1][r][1] += (v1 <= mq1);
        c[1][r][2] += (v1 <= mq2);
        c[1][r][3] += (v1 <= mq3);
      }
    }

    if (s < 5){
      stage_write(p ^ 1);                    // write late, after compute consumed buf p
      __syncthreads();
    }
  }

  // reduce over the 16 column-lanes, then shell diffs + atomics
  #pragma unroll
  for (int mf = 0; mf < 2; mf++)
    #pragma unroll
    for (int r = 0; r < 4; r++)
      #pragma unroll
      for (int t = 0; t < 4; t++){
        int v = (int)c[mf][r][t];
        v += __shfl_xor(v, 1); v += __shfl_xor(v, 2);
        v += __shfl_xor(v, 4); v += __shfl_xor(v, 8);
        c[mf][r][t] = (unsigned)v;
      }
  if (fr == 0){
    #pragma unroll
    for (int mf = 0; mf < 2; mf++)
      #pragma unroll
      for (int r = 0; r < 4; r++){
        int row = wrow0 + 16*mf + fg*4 + r;
        #pragma unroll
        for (int s = 0; s < 3; s++){
          unsigned o = c[mf][r][s] - c[mf][r][s + 1];
          if (o) atomicAdd(&cnt[row * 3 + s], o);
        }
      }
  }
}

// ---------------- K3: feats = comp + occ @ se_w^T + se_b ; occ output
__global__ __launch_bounds__(256) void k_feats(const float* __restrict__ comp,
    const unsigned* __restrict__ cnt, const float* __restrict__ se_w,
    const float* __restrict__ se_b, float* __restrict__ feats_out,
    float* __restrict__ occ_out)
{
  int tid = threadIdx.x; int lane = tid & 63; int w = tid >> 6;
  int row = blockIdx.x * 4 + w;
  const float denom = 1.081f * 12287.0f + 1e-8f;

  float o0 = (float)cnt[row * 3 + 0] / denom;
  float o1 = (float)cnt[row * 3 + 1] / denom;
  float o2 = (float)cnt[row * 3 + 2] / denom;

  {
    int d = lane;
    float v = comp[row * 92 + d]
            + o0 * se_w[d * 3 + 0] + o1 * se_w[d * 3 + 1] + o2 * se_w[d * 3 + 2]
            + se_b[d];
    feats_out[row * 92 + d] = v;
  }
  int d2 = lane + 64;
  if (d2 < 92){
    float v = comp[row * 92 + d2]
            + o0 * se_w[d2 * 3 + 0] + o1 * se_w[d2 * 3 + 1] + o2 * se_w[d2 * 3 + 2]
            + se_b[d2];
    feats_out[row * 92 + d2] = v;
  }
  if (lane < 3){
    float ov = (lane == 0) ? o0 : ((lane == 1) ? o1 : o2);
    occ_out[row * 3 + lane] = ov;
  }
}

extern "C" void kernel_launch(void* const* d_in, const int* in_sizes, int n_in,
                              void* d_out, int out_size, void* d_ws, size_t ws_size,
                              hipStream_t stream) {
  (void)in_sizes; (void)n_in; (void)out_size; (void)ws_size;

  const float* x = (const float*)d_in[0];
  const float* cw[4] = {(const float*)d_in[1], (const float*)d_in[5], (const float*)d_in[9],  (const float*)d_in[13]};
  const float* cb[4] = {(const float*)d_in[2], (const float*)d_in[6], (const float*)d_in[10], (const float*)d_in[14]};
  const float* sw[4] = {(const float*)d_in[3], (const float*)d_in[7], (const float*)d_in[11], (const float*)d_in[15]};
  const float* sb[4] = {(const float*)d_in[4], (const float*)d_in[8], (const float*)d_in[12], (const float*)d_in[16]};
  const float* shell_bnd = (const float*)d_in[17];
  const float* se_w = (const float*)d_in[18];
  const float* se_b = (const float*)d_in[19];
  const float* basin_c = (const float*)d_in[20];
  const float* basin_d = (const float*)d_in[21];
  const float* basin_w = (const float*)d_in[22];

  char* ws = (char*)d_ws;
  float*    comp  = (float*)(ws);                    // 12288*92*4   = 4,521,984
  u16*      Cbf   = (u16*)  (ws + 4521984);          // 12288*96*2   = 2,359,296
  float*    nrm2  = (float*)(ws + 6881280);          // 12288*4      =    49,152
  unsigned* cnt   = (unsigned*)(ws + 6930432);       // 12288*3*4    =   147,456
  u16*      slabs = (u16*)  (ws + 7077888);          // 8*16384*2    =   262,144

  float* out = (float*)d_out;
  float* feats_out  = out;                 // 12288*92
  float* energy_out = out + 1130496;       // 12288
  float* probs_out  = out + 1142784;       // 12288*8
  float* occ_out    = out + 1241088;       // 12288*3

  hipMemsetAsync(cnt, 0, 147456, stream);

  k_wconv8<<<512, 256, 0, stream>>>(cw[0], sw[0], cw[1], sw[1], cw[2], sw[2], cw[3], sw[3],
                                    slabs);

  k_mlp<<<384, 256, 0, stream>>>(x, slabs,
      cb[0], cb[1], cb[2], cb[3], sb[0], sb[1], sb[2], sb[3], comp);

  k_rowfin<<<3072, 256, 0, stream>>>(comp, Cbf, nrm2, basin_c, basin_d, basin_w,
                                     energy_out, probs_out);

  k_pdist<<<3072, 256, 0, stream>>>(Cbf, nrm2, shell_bnd, cnt);

  k_feats<<<3072, 256, 0, stream>>>(comp, cnt, se_w, se_b, feats_out, occ_out);
}

// Round 4
// 137.425 us; speedup vs baseline: 1.5405x; 1.5405x over previous
//
#include <hip/hip_runtime.h>
#include <hip/hip_bf16.h>

typedef __attribute__((ext_vector_type(8))) short bf16x8;
typedef __attribute__((ext_vector_type(4))) float f32x4;
typedef unsigned short u16;

#define BATCH 12288

__device__ __forceinline__ u16 f2bf(float f){
  __hip_bfloat16 h = __float2bfloat16(f);
  return *reinterpret_cast<u16*>(&h);
}
__device__ __forceinline__ float bf2f(u16 u){
  __hip_bfloat16 h; *reinterpret_cast<u16*>(&h) = u;
  return __bfloat162float(h);
}
__device__ __forceinline__ f32x4 mfma16(bf16x8 a, bf16x8 b, f32x4 c){
  return __builtin_amdgcn_mfma_f32_16x16x32_bf16(a, b, c, 0, 0, 0);
}
__device__ __forceinline__ float softplusf(float v){ return log1pf(expf(v)); }

// ---------------- K0: all 8 weight matrices -> zero-padded [128][128] bf16 slabs
__global__ __launch_bounds__(256) void k_wconv8(
    const float* __restrict__ s0, const float* __restrict__ s1,
    const float* __restrict__ s2, const float* __restrict__ s3,
    const float* __restrict__ s4, const float* __restrict__ s5,
    const float* __restrict__ s6, const float* __restrict__ s7,
    u16* __restrict__ dst)
{
  int blk = blockIdx.x;            // 512 blocks: 8 slabs x 64
  int slab = blk >> 6;
  const float* src; int rows, cols;
  switch (slab){
    case 0: src = s0; rows = 118; cols = 128; break;
    case 1: src = s1; rows = 118; cols = 128; break;
    case 2: src = s2; rows = 109; cols = 118; break;
    case 3: src = s3; rows = 109; cols = 128; break;
    case 4: src = s4; rows = 100; cols = 109; break;
    case 5: src = s5; rows = 100; cols = 128; break;
    case 6: src = s6; rows =  92; cols = 100; break;
    default: src = s7; rows =  92; cols = 128; break;
  }
  int idx = (blk & 63) * 256 + threadIdx.x;       // 16384 per slab
  int r = idx >> 7, c = idx & 127;
  float v = (r < rows && c < cols) ? src[r * cols + c] : 0.f;
  dst[slab * 16384 + idx] = f2bf(v);
}

// ---------------- K1: 4-layer compression MLP via MFMA (32 rows / block)
__global__ __launch_bounds__(256) void k_mlp(const float* __restrict__ x,
    const u16* __restrict__ slabs,
    const float* __restrict__ cb0, const float* __restrict__ cb1,
    const float* __restrict__ cb2, const float* __restrict__ cb3,
    const float* __restrict__ sb0, const float* __restrict__ sb1,
    const float* __restrict__ sb2, const float* __restrict__ sb3,
    float* __restrict__ comp)
{
  const int LSTR = 136;                       // LDS row stride (bf16 elems)
  __shared__ u16 xbf[32 * 136];
  __shared__ u16 act[2][32 * 136];
  int tid = threadIdx.x;
  int lane = tid & 63, w = tid >> 6;
  int fr = lane & 15, fg = lane >> 4;
  int r0 = blockIdx.x * 32;

  // stage x (f32 -> bf16) into LDS
  #pragma unroll
  for (int i = 0; i < 4; i++){
    int slot = tid + i * 256;                 // 1024 float4 slots = 32 rows * 32
    int row = slot >> 5, c4 = slot & 31;
    float4 v = *reinterpret_cast<const float4*>(&x[(r0 + row) * 128 + c4 * 4]);
    ushort4 pk;
    pk.x = f2bf(v.x); pk.y = f2bf(v.y); pk.z = f2bf(v.z); pk.w = f2bf(v.w);
    *reinterpret_cast<ushort4*>(&xbf[row * LSTR + c4 * 4]) = pk;
  }
  __syncthreads();

  // x A-fragments kept in registers for all skip GEMMs
  bf16x8 xa[2][4];
  #pragma unroll
  for (int mf = 0; mf < 2; mf++)
    #pragma unroll
    for (int kc = 0; kc < 4; kc++)
      xa[mf][kc] = *reinterpret_cast<const bf16x8*>(&xbf[(16*mf + fr) * LSTR + kc*32 + fg*8]);

  const float* cbs[4] = {cb0, cb1, cb2, cb3};
  const float* sbs[4] = {sb0, sb1, sb2, sb3};
  const int douts[4] = {118, 109, 100, 92};

  #pragma unroll
  for (int s = 0; s < 4; s++){
    const u16* aIn  = (s == 0) ? xbf : &act[(s + 1) & 1][0];
    u16*       aOut = &act[s & 1][0];
    const u16* cwS = slabs + (2*s)     * 16384;
    const u16* swS = slabs + (2*s + 1) * 16384;
    const float* cb = cbs[s];
    const float* sb = sbs[s];
    int dout = douts[s];

    bf16x8 af[2][4];
    #pragma unroll
    for (int mf = 0; mf < 2; mf++)
      #pragma unroll
      for (int kc = 0; kc < 4; kc++)
        af[mf][kc] = *reinterpret_cast<const bf16x8*>(&aIn[(16*mf + fr) * LSTR + kc*32 + fg*8]);

    f32x4 ac1[2][2], ac2[2][2];
    #pragma unroll
    for (int mf = 0; mf < 2; mf++)
      #pragma unroll
      for (int nf = 0; nf < 2; nf++){
        ac1[mf][nf] = (f32x4){0.f,0.f,0.f,0.f};
        ac2[mf][nf] = (f32x4){0.f,0.f,0.f,0.f};
      }

    #pragma unroll
    for (int nf = 0; nf < 2; nf++){
      int o = 32*w + 16*nf + fr;              // output col this lane supplies as B-row
      #pragma unroll
      for (int kc = 0; kc < 4; kc++){
        bf16x8 b1 = *reinterpret_cast<const bf16x8*>(&cwS[o * 128 + kc*32 + fg*8]);
        bf16x8 b2 = *reinterpret_cast<const bf16x8*>(&swS[o * 128 + kc*32 + fg*8]);
        ac1[0][nf] = mfma16(af[0][kc], b1, ac1[0][nf]);
        ac1[1][nf] = mfma16(af[1][kc], b1, ac1[1][nf]);
        ac2[0][nf] = mfma16(xa[0][kc], b2, ac2[0][nf]);
        ac2[1][nf] = mfma16(xa[1][kc], b2, ac2[1][nf]);
      }
    }

    #pragma unroll
    for (int nf = 0; nf < 2; nf++){
      int col = 32*w + 16*nf + fr;
      float cbv = (col < dout) ? cb[col] : 0.f;
      float sbv = (col < dout) ? sb[col] : 0.f;
      #pragma unroll
      for (int mf = 0; mf < 2; mf++){
        #pragma unroll
        for (int r = 0; r < 4; r++){
          float t1 = ac1[mf][nf][r] + cbv;
          float g = 0.5f * t1 * (1.f + erff(t1 * 0.70710678118654752f));
          float v = g + 0.1f * (ac2[mf][nf][r] + sbv);
          int row = 16*mf + fg*4 + r;
          if (s < 3){
            aOut[row * LSTR + col] = (col < dout) ? f2bf(v) : (u16)0;
          } else {
            if (col < 92) comp[(r0 + row) * 92 + col] = v;
          }
        }
      }
    }
    __syncthreads();
  }
}

// ---------------- K2a: per-row finalize: bf16 C (padded 96), -0.5*norms, energy, basin probs
__global__ __launch_bounds__(256) void k_rowfin(const float* __restrict__ comp,
    u16* __restrict__ Cbf, float* __restrict__ nrm2,
    const float* __restrict__ basin_c, const float* __restrict__ basin_d,
    const float* __restrict__ basin_w,
    float* __restrict__ energy_out, float* __restrict__ probs_out)
{
  int tid = threadIdx.x; int lane = tid & 63; int w = tid >> 6;
  int row = blockIdx.x * 4 + w;

  float c0 = comp[row * 92 + lane];
  int d2i = 64 + lane;
  float c1 = (d2i < 92) ? comp[row * 92 + d2i] : 0.f;

  u16 b0 = f2bf(c0);
  u16 b1 = (d2i < 92) ? f2bf(c1) : (u16)0;
  Cbf[row * 96 + lane] = b0;
  if (lane < 32) Cbf[row * 96 + 64 + lane] = b1;   // cols 64..95 (92..95 zero pad)

  // row norm from the *bf16* values (consistency with MFMA gram); store -0.5*|c|^2
  float f0 = bf2f(b0), f1 = bf2f(b1);
  float ns = f0*f0 + f1*f1;
  #pragma unroll
  for (int m = 1; m < 64; m <<= 1) ns += __shfl_xor(ns, m);
  if (lane == 0) nrm2[row] = -0.5f * ns;

  // basin distances (f32 compressed)
  float bd[8];
  #pragma unroll
  for (int b = 0; b < 8; b++){
    float e0 = c0 - basin_c[b * 92 + lane];
    float p = e0 * e0;
    if (d2i < 92){ float e1 = c1 - basin_c[b * 92 + d2i]; p += e1 * e1; }
    #pragma unroll
    for (int m = 1; m < 64; m <<= 1) p += __shfl_xor(p, m);
    bd[b] = sqrtf(p);
  }
  float z[8]; float mx = -1e30f;
  #pragma unroll
  for (int b = 0; b < 8; b++){
    float wd = softplusf(basin_w[b]);
    z[b] = -bd[b] / wd;
    mx = fmaxf(mx, z[b]);
  }
  float p8[8]; float ssum = 0.f;
  #pragma unroll
  for (int b = 0; b < 8; b++){ p8[b] = expf(z[b] - mx); ssum += p8[b]; }
  float inv = 1.f / ssum; float en = 0.f;
  #pragma unroll
  for (int b = 0; b < 8; b++){ p8[b] *= inv; en += p8[b] * basin_d[b]; }

  if (lane == 0) energy_out[row] = en;
  if (lane < 8){
    float v = (lane & 4) ? ((lane & 2) ? ((lane & 1) ? p8[7] : p8[6])
                                       : ((lane & 1) ? p8[5] : p8[4]))
                         : ((lane & 2) ? ((lane & 1) ? p8[3] : p8[2])
                                       : ((lane & 1) ? p8[1] : p8[0]));
    probs_out[row * 8 + lane] = v;
  }
}

// ---------------- K2b: pairwise-distance shell histogram via bf16 MFMA gram
// C-init trick: accum starts at -0.5(|a|^2+|b|^2); after gram MFMAs, D = -0.5*d^2.
// Shell test d^2 >= q  <=>  D <= -q^2/2 (precomputed). Round-2 staging structure
// (load->ds_write in one step, NO register-held tile: avoids scratch spill).
__global__ __launch_bounds__(256, 4) void k_pdist(const u16* __restrict__ Cbf,
    const float* __restrict__ nrm2, const float* __restrict__ shell_bnd,
    unsigned* __restrict__ cnt)
{
  __shared__ u16 Bs[2][64 * 104];   // 104-elem stride: 13x16B granules, conflict-benign
  __shared__ float Ns[2][64];
  int tid = threadIdx.x; int lane = tid & 63; int w = tid >> 6;
  int fr = lane & 15, fg = lane >> 4;
  int blk = blockIdx.x;
  int ib = blk % 96, jc = blk / 96;         // 96 i-tiles x 32 j-chunks
  int i0 = ib * 128, j0 = jc * 384;

  float q0 = softplusf(shell_bnd[0]); float mq0 = -0.5f * q0 * q0;
  float q1 = softplusf(shell_bnd[1]); float mq1 = -0.5f * q1 * q1;
  float q2 = softplusf(shell_bnd[2]); float mq2 = -0.5f * q2 * q2;
  float q3 = softplusf(shell_bnd[3]); float mq3 = -0.5f * q3 * q3;

  int wrow0 = i0 + 32 * w;
  bf16x8 A[2][3];
  #pragma unroll
  for (int mf = 0; mf < 2; mf++)
    #pragma unroll
    for (int kc = 0; kc < 3; kc++)
      A[mf][kc] = *reinterpret_cast<const bf16x8*>(&Cbf[(wrow0 + 16*mf + fr) * 96 + kc*32 + fg*8]);

  float hr[2][4];                            // -0.5*|row|^2
  #pragma unroll
  for (int mf = 0; mf < 2; mf++)
    #pragma unroll
    for (int r = 0; r < 4; r++)
      hr[mf][r] = nrm2[wrow0 + 16*mf + fg*4 + r];

  unsigned c[2][4][4];
  #pragma unroll
  for (int mf = 0; mf < 2; mf++)
    #pragma unroll
    for (int r = 0; r < 4; r++)
      #pragma unroll
      for (int t = 0; t < 4; t++) c[mf][r][t] = 0u;

  // staging offsets (hoisted): 768 chunks of 16B = 64 rows x 12
  int srcR[3], srcS[3], dstL[3];
  #pragma unroll
  for (int t = 0; t < 3; t++){
    int ch = tid + t * 256;
    int rr = ch / 12, sl = ch - rr * 12;
    srcR[t] = rr; srcS[t] = sl * 8;
    dstL[t] = rr * 104 + sl * 8;
  }

  // stage step 0
  {
    int jr0 = j0;
    #pragma unroll
    for (int t = 0; t < 3; t++)
      *reinterpret_cast<bf16x8*>(&Bs[0][dstL[t]]) =
        *reinterpret_cast<const bf16x8*>(&Cbf[(jr0 + srcR[t]) * 96 + srcS[t]]);
    if (tid < 64) Ns[0][tid] = nrm2[jr0 + tid];
  }
  __syncthreads();

  for (int s = 0; s < 6; s++){
    int p = s & 1;
    if (s < 5){
      int jr0 = j0 + (s + 1) * 64;           // stage next into p^1 (consumed last iter)
      #pragma unroll
      for (int t = 0; t < 3; t++)
        *reinterpret_cast<bf16x8*>(&Bs[p ^ 1][dstL[t]]) =
          *reinterpret_cast<const bf16x8*>(&Cbf[(jr0 + srcR[t]) * 96 + srcS[t]]);
      if (tid < 64) Ns[p ^ 1][tid] = nrm2[jr0 + tid];
    }

    #pragma unroll
    for (int nt = 0; nt < 4; nt++){
      bf16x8 B0 = *reinterpret_cast<const bf16x8*>(&Bs[p][(nt*16 + fr) * 104 + 0*32 + fg*8]);
      bf16x8 B1 = *reinterpret_cast<const bf16x8*>(&Bs[p][(nt*16 + fr) * 104 + 1*32 + fg*8]);
      bf16x8 B2 = *reinterpret_cast<const bf16x8*>(&Bs[p][(nt*16 + fr) * 104 + 2*32 + fg*8]);
      float hc = Ns[p][nt*16 + fr];

      f32x4 g0, g1;
      #pragma unroll
      for (int r = 0; r < 4; r++){ g0[r] = hr[0][r] + hc; g1[r] = hr[1][r] + hc; }
      g0 = mfma16(A[0][0], B0, g0); g0 = mfma16(A[0][1], B1, g0); g0 = mfma16(A[0][2], B2, g0);
      g1 = mfma16(A[1][0], B0, g1); g1 = mfma16(A[1][1], B1, g1); g1 = mfma16(A[1][2], B2, g1);

      #pragma unroll
      for (int r = 0; r < 4; r++){
        float v0 = g0[r], v1 = g1[r];
        c[0][r][0] += (v0 <= mq0);
        c[0][r][1] += (v0 <= mq1);
        c[0][r][2] += (v0 <= mq2);
        c[0][r][3] += (v0 <= mq3);
        c[1][r][0] += (v1 <= mq0);
        c[1][r][1] += (v1 <= mq1);
        c[1][r][2] += (v1 <= mq2);
        c[1][r][3] += (v1 <= mq3);
      }
    }
    __syncthreads();
  }

  // reduce over the 16 column-lanes, then shell diffs + atomics
  #pragma unroll
  for (int mf = 0; mf < 2; mf++)
    #pragma unroll
    for (int r = 0; r < 4; r++)
      #pragma unroll
      for (int t = 0; t < 4; t++){
        int v = (int)c[mf][r][t];
        v += __shfl_xor(v, 1); v += __shfl_xor(v, 2);
        v += __shfl_xor(v, 4); v += __shfl_xor(v, 8);
        c[mf][r][t] = (unsigned)v;
      }
  if (fr == 0){
    #pragma unroll
    for (int mf = 0; mf < 2; mf++)
      #pragma unroll
      for (int r = 0; r < 4; r++){
        int row = wrow0 + 16*mf + fg*4 + r;
        #pragma unroll
        for (int s = 0; s < 3; s++){
          unsigned o = c[mf][r][s] - c[mf][r][s + 1];
          if (o) atomicAdd(&cnt[row * 3 + s], o);
        }
      }
  }
}

// ---------------- K3: feats = comp + occ @ se_w^T + se_b ; occ output
__global__ __launch_bounds__(256) void k_feats(const float* __restrict__ comp,
    const unsigned* __restrict__ cnt, const float* __restrict__ se_w,
    const float* __restrict__ se_b, float* __restrict__ feats_out,
    float* __restrict__ occ_out)
{
  int tid = threadIdx.x; int lane = tid & 63; int w = tid >> 6;
  int row = blockIdx.x * 4 + w;
  const float denom = 1.081f * 12287.0f + 1e-8f;

  float o0 = (float)cnt[row * 3 + 0] / denom;
  float o1 = (float)cnt[row * 3 + 1] / denom;
  float o2 = (float)cnt[row * 3 + 2] / denom;

  {
    int d = lane;
    float v = comp[row * 92 + d]
            + o0 * se_w[d * 3 + 0] + o1 * se_w[d * 3 + 1] + o2 * se_w[d * 3 + 2]
            + se_b[d];
    feats_out[row * 92 + d] = v;
  }
  int d2 = lane + 64;
  if (d2 < 92){
    float v = comp[row * 92 + d2]
            + o0 * se_w[d2 * 3 + 0] + o1 * se_w[d2 * 3 + 1] + o2 * se_w[d2 * 3 + 2]
            + se_b[d2];
    feats_out[row * 92 + d2] = v;
  }
  if (lane < 3){
    float ov = (lane == 0) ? o0 : ((lane == 1) ? o1 : o2);
    occ_out[row * 3 + lane] = ov;
  }
}

extern "C" void kernel_launch(void* const* d_in, const int* in_sizes, int n_in,
                              void* d_out, int out_size, void* d_ws, size_t ws_size,
                              hipStream_t stream) {
  (void)in_sizes; (void)n_in; (void)out_size; (void)ws_size;

  const float* x = (const float*)d_in[0];
  const float* cw[4] = {(const float*)d_in[1], (const float*)d_in[5], (const float*)d_in[9],  (const float*)d_in[13]};
  const float* cb[4] = {(const float*)d_in[2], (const float*)d_in[6], (const float*)d_in[10], (const float*)d_in[14]};
  const float* sw[4] = {(const float*)d_in[3], (const float*)d_in[7], (const float*)d_in[11], (const float*)d_in[15]};
  const float* sb[4] = {(const float*)d_in[4], (const float*)d_in[8], (const float*)d_in[12], (const float*)d_in[16]};
  const float* shell_bnd = (const float*)d_in[17];
  const float* se_w = (const float*)d_in[18];
  const float* se_b = (const float*)d_in[19];
  const float* basin_c = (const float*)d_in[20];
  const float* basin_d = (const float*)d_in[21];
  const float* basin_w = (const float*)d_in[22];

  char* ws = (char*)d_ws;
  float*    comp  = (float*)(ws);                    // 12288*92*4   = 4,521,984
  u16*      Cbf   = (u16*)  (ws + 4521984);          // 12288*96*2   = 2,359,296
  float*    nrm2  = (float*)(ws + 6881280);          // 12288*4      =    49,152
  unsigned* cnt   = (unsigned*)(ws + 6930432);       // 12288*3*4    =   147,456
  u16*      slabs = (u16*)  (ws + 7077888);          // 8*16384*2    =   262,144

  float* out = (float*)d_out;
  float* feats_out  = out;                 // 12288*92
  float* energy_out = out + 1130496;       // 12288
  float* probs_out  = out + 1142784;       // 12288*8
  float* occ_out    = out + 1241088;       // 12288*3

  hipMemsetAsync(cnt, 0, 147456, stream);

  k_wconv8<<<512, 256, 0, stream>>>(cw[0], sw[0], cw[1], sw[1], cw[2], sw[2], cw[3], sw[3],
                                    slabs);

  k_mlp<<<384, 256, 0, stream>>>(x, slabs,
      cb[0], cb[1], cb[2], cb[3], sb[0], sb[1], sb[2], sb[3], comp);

  k_rowfin<<<3072, 256, 0, stream>>>(comp, Cbf, nrm2, basin_c, basin_d, basin_w,
                                     energy_out, probs_out);

  k_pdist<<<3072, 256, 0, stream>>>(Cbf, nrm2, shell_bnd, cnt);

  k_feats<<<3072, 256, 0, stream>>>(comp, cnt, se_w, se_b, feats_out, occ_out);
}